// Round 1
// 278.651 us; speedup vs baseline: 1.0455x; 1.0455x over previous
//
#include <hip/hip_runtime.h>
#include <math.h>

#define IMGN 32
#define HT 1024
#define WD 1024
#define IMG_STRIDE (HT*WD)
#define LOSS_THR_F 120.0f
#define MMX_BLOCKS 4096

// ---------------- pass 1: global min/max of width-deltas ----------------
// Each wave handles 2 complete 1024-float rows as 8 coalesced float4 loads,
// all issued before any use (deep ILP). Left-neighbors via register shuffles.
// No scalar loads, no divergence, no atomics.
__global__ __launch_bounds__(256) void k_minmax(const float* __restrict__ x,
                                                float* __restrict__ wsf){
  const int lane = threadIdx.x & 63;
  const int wave_id = (blockIdx.x*256 + threadIdx.x) >> 6;   // 0..16383
  const float4* x4 = (const float4*)x;
  const int base4 = wave_id * 512;        // 512 float4 = 2048 floats = 2 rows

  float4 v[8];
  #pragma unroll
  for (int j = 0; j < 8; ++j) v[j] = x4[base4 + j*64 + lane];

  float lmin = INFINITY, lmax = -INFINITY;
  #pragma unroll
  for (int j = 0; j < 8; ++j){
    float lf = __shfl_up(v[j].w, 1);
    // chunks 0 and 4 start a 1024-wide row: delta = x - 0
    float carry = (j == 0 || j == 4) ? 0.0f : __shfl(v[j-1].w, 63);
    if (lane == 0) lf = carry;
    float d0 = v[j].x - lf,      d1 = v[j].y - v[j].x;
    float d2 = v[j].z - v[j].y,  d3 = v[j].w - v[j].z;
    lmin = fminf(lmin, fminf(fminf(d0, d1), fminf(d2, d3)));
    lmax = fmaxf(lmax, fmaxf(fmaxf(d0, d1), fmaxf(d2, d3)));
  }
  #pragma unroll
  for (int off = 32; off; off >>= 1){
    lmin = fminf(lmin, __shfl_xor(lmin, off));
    lmax = fmaxf(lmax, __shfl_xor(lmax, off));
  }
  __shared__ float smin[4], smax[4];
  int wv = threadIdx.x >> 6;
  if (lane == 0){ smin[wv] = lmin; smax[wv] = lmax; }
  __syncthreads();
  if (threadIdx.x == 0){
    wsf[2*blockIdx.x]   = fminf(fminf(smin[0], smin[1]), fminf(smin[2], smin[3]));
    wsf[2*blockIdx.x+1] = fmaxf(fmaxf(smax[0], smax[1]), fmaxf(smax[2], smax[3]));
  }
}

// single-block reduction of the 4096 partials -> wsf[2*MMX_BLOCKS .. +1]
__global__ __launch_bounds__(256) void k_reduce(float* __restrict__ wsf){
  int t = threadIdx.x;
  float mn = INFINITY, mx = -INFINITY;
  #pragma unroll
  for (int j = 0; j < MMX_BLOCKS/256; ++j){
    float2 p = ((const float2*)wsf)[t + 256*j];
    mn = fminf(mn, p.x); mx = fmaxf(mx, p.y);
  }
  #pragma unroll
  for (int off = 32; off; off >>= 1){
    mn = fminf(mn, __shfl_xor(mn, off));
    mx = fmaxf(mx, __shfl_xor(mx, off));
  }
  __shared__ float smin[4], smax[4];
  int wv = t >> 6;
  if ((t & 63) == 0){ smin[wv] = mn; smax[wv] = mx; }
  __syncthreads();
  if (t == 0){
    wsf[2*MMX_BLOCKS]   = fminf(fminf(smin[0], smin[1]), fminf(smin[2], smin[3]));
    wsf[2*MMX_BLOCKS+1] = fmaxf(fmaxf(smax[0], smax[1]), fmaxf(smax[2], smax[3]));
  }
}

// ---------------- pass 2: per-8x8-block fit + output ----------------
// one 512-thread WG per (8 rows x 32 cols x 32 imgs) tile = 4 sub-blocks.
__global__ __launch_bounds__(512) void k_main(const float* __restrict__ x,
                                              float* __restrict__ out,
                                              const float* __restrict__ wsf){
  // dsh[s][p][i]: sub-block stride 2113, pixel stride 33 -> all patterns
  // are <=2-way bank-aliased (free) or broadcast.
  __shared__ float dsh[4*2113];
  __shared__ float s_inv[4][9];
  __shared__ int   s_degen[4];

  const int tid = threadIdx.x;
  const int bid = blockIdx.x;
  const int xcd = bid & 7;
  const int jj  = bid >> 3;
  const int hb  = xcd*16 + (jj >> 5);
  const int cb  = jj & 31;
  const int row0 = hb << 3;
  const int col0 = cb << 5;

  const float mn = wsf[2*MMX_BLOCKS];
  const float mx = wsf[2*MMX_BLOCKS+1];
  const bool  neq = (mx != mn);
  const float scale = neq ? (65535.0f / (mx - mn)) : 1.0f;
  const float sinv  = 1.0f / scale;
  const float moff  = neq ? mn : 0.0f;
  // lsb is an exact power of 2 -> division by it == multiplication by ilsb
  const float e1   = rintf(log2f(mx * (1.0f/32768.0f))) + 1.0f;
  const float lsb  = exp2f(e1);
  const float ilsb = exp2f(-e1);

  // ---- k-invariant index decomposition (f = tid + 512k; 512 % 64 == 0,
  // so rem/r/fi/s/p are k-invariant and only i = i0 + 8k changes) ----
  const int rem = tid & 63;
  const int r   = rem >> 3;          // row within 8-row tile
  const int fi  = rem & 7;           // float4 within 32-col tile
  const int i0  = tid >> 6;          // image 0..7 (+8k)
  const int sB0 = fi >> 1;           // sub-block of this lane's float4
  const int pp  = (r << 3) + ((fi & 1) << 2);
  const int lbase0 = sB0*2113 + pp*33 + i0;
  const int gc0 = col0 + (fi << 2);
  const size_t elt0 = (size_t)i0*IMG_STRIDE + (size_t)(row0+r)*WD + gc0;

  // ---- phase 1: load + delta + quantize/dequant -> dsh.
  // Left-neighbor via __shfl_up (lane-1 holds cols gc0-4..gc0-1); only the
  // fi==0 lanes (tile's left edge) need a scalar global load.
  // keep[] carries {lf, v.x, v.y, v.z} to phase 4 so x is read exactly once.
  float4 keep[4];
  #pragma unroll
  for (int k = 0; k < 4; ++k){
    const size_t elt = elt0 + (size_t)(k << 3)*IMG_STRIDE;
    float4 v = *(const float4*)(x + elt);
    float lf = __shfl_up(v.w, 1);
    if (fi == 0) lf = col0 ? x[elt - 1] : 0.0f;
    keep[k] = make_float4(lf, v.x, v.y, v.z);
    float d0 = v.x - lf, d1 = v.y - v.x, d2 = v.z - v.y, d3 = v.w - v.z;
    float q0, q1, q2, q3;
    if (neq){
      q0 = __fadd_rn(__fmul_rn(rintf((d0 - mn) * scale), sinv), moff);
      q1 = __fadd_rn(__fmul_rn(rintf((d1 - mn) * scale), sinv), moff);
      q2 = __fadd_rn(__fmul_rn(rintf((d2 - mn) * scale), sinv), moff);
      q3 = __fadd_rn(__fmul_rn(rintf((d3 - mn) * scale), sinv), moff);
    } else { q0 = d0; q1 = d1; q2 = d2; q3 = d3; }
    const int base = lbase0 + (k << 3);
    dsh[base]      = q0;
    dsh[base + 33] = q1;
    dsh[base + 66] = q2;
    dsh[base + 99] = q3;
  }
  __syncthreads();

  // ---- phase 2: 3x3 normal matrix per sub-block (wave w -> sub-block w)
  if (tid < 256){
    int s = tid >> 6;
    int p = tid & 63;
    float a0 = dsh[s*2113 + p*33 + 0];
    float a1 = dsh[s*2113 + p*33 + 1];
    double s00 = (double)a0*a0, s01 = (double)a0*a1, s02 = a0;
    double s11 = (double)a1*a1, s12 = a1;
    float mx0 = a0, mn0 = a0, mx1 = a1, mn1 = a1;
    #pragma unroll
    for (int off = 32; off; off >>= 1){
      s00 += __shfl_xor(s00, off);
      s01 += __shfl_xor(s01, off);
      s02 += __shfl_xor(s02, off);
      s11 += __shfl_xor(s11, off);
      s12 += __shfl_xor(s12, off);
      mx0 = fmaxf(mx0, __shfl_xor(mx0, off));
      mn0 = fminf(mn0, __shfl_xor(mn0, off));
      mx1 = fmaxf(mx1, __shfl_xor(mx1, off));
      mn1 = fminf(mn1, __shfl_xor(mn1, off));
    }
    if (p == 0){
      double a = (float)s00, b = (float)s01, c = (float)s02;
      double d = (float)s11, e = (float)s12, f = 64.0;
      double c00 = d*f - e*e;
      double c01 = c*e - b*f;
      double c02 = b*e - c*d;
      double det = a*c00 + b*c01 + c*c02;
      float inv[9];
      if (det == 0.0){
        inv[0]=1.f;inv[1]=0.f;inv[2]=0.f;
        inv[3]=0.f;inv[4]=1.f;inv[5]=0.f;
        inv[6]=0.f;inv[7]=0.f;inv[8]=1.f;
      } else {
        double id = 1.0/det;
        double c11 = a*f - c*c;
        double c12 = b*c - a*e;
        double c22 = a*d - b*b;
        inv[0]=(float)(c00*id); inv[1]=(float)(c01*id); inv[2]=(float)(c02*id);
        inv[3]=inv[1];          inv[4]=(float)(c11*id); inv[5]=(float)(c12*id);
        inv[6]=inv[2];          inv[7]=inv[5];          inv[8]=(float)(c22*id);
      }
      #pragma unroll
      for (int q = 0; q < 9; ++q) s_inv[s][q] = inv[q];
      s_degen[s] = (((mx0 - mn0) < 1e-6f) && ((mx1 - mn1) < 1e-6f)) ? 1 : 0;
    }
  }
  __syncthreads();

  // ---- phase 3: per-image fit. Stage ALL reads, barrier, write rr back.
  const int i_img = (tid >> 3) & 31;
  const int sub   = tid & 7;
  const int p0    = sub << 3;

  float dv[2][8], a0v[2][8], a1v[2][8];
  int ss[2];
  #pragma unroll
  for (int k = 0; k < 2; ++k){
    int sB = ((tid >> 8) << 1) + k; ss[k] = sB;
    int sb = sB*2113;
    #pragma unroll
    for (int c2 = 0; c2 < 8; ++c2){
      int off = sb + (p0 + c2)*33;
      dv[k][c2]  = dsh[off + i_img];
      a0v[k][c2] = dsh[off + 0];
      a1v[k][c2] = dsh[off + 1];
    }
  }
  #pragma unroll
  for (int k = 0; k < 2; ++k){
    const int sB = ss[k];
    const float i00 = s_inv[sB][0], i01 = s_inv[sB][1], i02 = s_inv[sB][2];
    const float i10 = s_inv[sB][3], i11 = s_inv[sB][4], i12 = s_inv[sB][5];
    const float i20 = s_inv[sB][6], i21 = s_inv[sB][7], i22 = s_inv[sB][8];

    float pc0 = 0.f, pc1 = 0.f, pc2v = 0.f;
    #pragma unroll
    for (int c2 = 0; c2 < 8; ++c2){
      float b0 = __fadd_rn(__fmaf_rn(i01, a1v[k][c2], __fmul_rn(i00, a0v[k][c2])), i02);
      float b1 = __fadd_rn(__fmaf_rn(i11, a1v[k][c2], __fmul_rn(i10, a0v[k][c2])), i12);
      float b2 = __fadd_rn(__fmaf_rn(i21, a1v[k][c2], __fmul_rn(i20, a0v[k][c2])), i22);
      pc0  = __fmaf_rn(b0, dv[k][c2], pc0);
      pc1  = __fmaf_rn(b1, dv[k][c2], pc1);
      pc2v = __fmaf_rn(b2, dv[k][c2], pc2v);
    }
    pc0  += __shfl_xor(pc0, 1);  pc0  += __shfl_xor(pc0, 2);  pc0  += __shfl_xor(pc0, 4);
    pc1  += __shfl_xor(pc1, 1);  pc1  += __shfl_xor(pc1, 2);  pc1  += __shfl_xor(pc1, 4);
    pc2v += __shfl_xor(pc2v, 1); pc2v += __shfl_xor(pc2v, 2); pc2v += __shfl_xor(pc2v, 4);

    float r1v[8];
    float loss = 0.f;
    #pragma unroll
    for (int c2 = 0; c2 < 8; ++c2){
      float rv = __fadd_rn(__fmaf_rn(a1v[k][c2], pc1, __fmul_rn(a0v[k][c2], pc0)), pc2v);
      // lsb is a power of 2: rv/lsb == rv*ilsb exactly (same rounding)
      float r1 = __fmul_rn(rintf(__fmul_rn(rv, ilsb)), lsb);
      r1v[c2] = r1;
      float df = __fsub_rn(dv[k][c2], r1);
      loss = __fadd_rn(loss, __fmul_rn(df, df));
    }
    loss += __shfl_xor(loss, 1); loss += __shfl_xor(loss, 2); loss += __shfl_xor(loss, 4);
    const bool sel = (!s_degen[sB]) && (loss <= LOSS_THR_F);
    #pragma unroll
    for (int c2 = 0; c2 < 8; ++c2)
      dv[k][c2] = sel ? r1v[c2] : dv[k][c2];     // rr in registers
  }
  __syncthreads();                                // all reads done everywhere
  #pragma unroll
  for (int k = 0; k < 2; ++k){
    int sb = ss[k]*2113;
    #pragma unroll
    for (int c2 = 0; c2 < 8; ++c2)
      dsh[sb + (p0 + c2)*33 + i_img] = dv[k][c2]; // rr -> LDS
  }
  __syncthreads();

  // ---- phase 4: coalesced epilogue, x_left from registers (no x re-read)
  #pragma unroll
  for (int k = 0; k < 4; ++k){
    const int base = lbase0 + (k << 3);
    const size_t elt = elt0 + (size_t)(k << 3)*IMG_STRIDE;
    float4 o;
    o.x = dsh[base]      + keep[k].x;
    o.y = dsh[base + 33] + keep[k].y;
    o.z = dsh[base + 66] + keep[k].z;
    o.w = dsh[base + 99] + keep[k].w;
    *(float4*)(out + elt) = o;
  }
}

extern "C" void kernel_launch(void* const* d_in, const int* in_sizes, int n_in,
                              void* d_out, int out_size, void* d_ws, size_t ws_size,
                              hipStream_t stream) {
  const float* x = (const float*)d_in[0];
  float* out = (float*)d_out;
  float* wsf = (float*)d_ws;
  hipLaunchKernelGGL(k_minmax, dim3(MMX_BLOCKS), dim3(256), 0, stream, x, wsf);
  hipLaunchKernelGGL(k_reduce, dim3(1),          dim3(256), 0, stream, wsf);
  hipLaunchKernelGGL(k_main,   dim3(4096),       dim3(512), 0, stream, x, out, wsf);
}